// Round 4
// baseline (6511.240 us; speedup 1.0000x reference)
//
#include <hip/hip_runtime.h>

// Problem constants (from reference: T,B,C,H,W = 8,32,128,32,32)
#define TT 8
#define BB 32
#define CC 128
#define HH 32
#define WW 32
#define HW 1024                 // H*W
#define CHW (CC*HW)             // 131072, one image (t,b)
#define NPLANES (TT*BB)         // 256 images
#define SITES (BB*CC*HW)        // 4194304, elements per timestep
#define TBHW (TT*BB*HH*WW)      // 262144, elements per channel (BN stat count)
#define NCLASS 10

// ---------------------------------------------------------------------------
// Conv 3x3, stride 1, pad 1, no bias + fused BN partial-stats epilogue.
// Block = 128 threads = one (t,b) image x 8 output channels.
// Thread owns 1 row x 8 consecutive pixels (128 x 8 = 1024 px = full plane),
// acc[8 oc][8 px] in registers.
// Input channels staged 4-at-a-time in LDS (34x35 with zero halo; odd row
// stride -> worst-case 2-way bank conflict, which is free).
// Weights are read directly from global with block-uniform indices ->
// compiler emits s_load into SGPRs; v_fma takes the SGPR operand. No weight
// LDS traffic at all.
// XCD swizzle: 1-D grid, id=(m*16+g)*8+x8 -> all 16 oc-group blocks of image
// n=x8+8m share XCD n%8 (id%8 round-robin model), so the 16x re-read of each
// 512 KB image hits that XCD's L2 instead of bouncing through L3. Bijective,
// speed-only.
// Because the block covers the FULL plane of its 8 output channels, the BN
// partial sums (sum, sumsq) over the plane are complete at epilogue time:
// shfl-reduce across the 2 waves and write pstats[n*CC+oc] — this removes
// the standalone stats kernel's full 134 MB re-read per layer. Deterministic
// (no float atomics).
// ---------------------------------------------------------------------------
__global__ __launch_bounds__(128) void conv_kernel(const float* __restrict__ x,
                                                   const float* __restrict__ w,
                                                   float* __restrict__ y,
                                                   float* __restrict__ pstats) {
    __shared__ float xs[4][34][35];   // 18.6 KB, zero halo, odd stride
    const int tid = threadIdx.x;
    // XCD-aware decode (see header comment)
    const int id  = blockIdx.x;       // 0..4095
    const int x8  = id & 7;
    const int q   = id >> 3;
    const int oc0 = (q & 15) * 8;     // oc-group 0..15
    const int n   = x8 + 8 * (q >> 4);// image index (t*B + b), 0..255

    // zero LDS once: border stays zero; interior is rewritten every chunk
    for (int i = tid; i < 4 * 34 * 35; i += 128) ((float*)xs)[i] = 0.0f;

    const int r  = tid >> 2;          // output row 0..31
    const int c0 = (tid & 3) * 8;     // output col base (0,8,16,24)

    float acc[8][8];
#pragma unroll
    for (int o = 0; o < 8; ++o)
#pragma unroll
        for (int p = 0; p < 8; ++p) acc[o][p] = 0.0f;

    const float* xim = x + (size_t)n * CHW;

    for (int ci0 = 0; ci0 < CC; ci0 += 4) {
        __syncthreads();  // previous chunk's compute done before overwrite
        // stage 4 input planes (coalesced float4; 2 per thread per plane)
#pragma unroll
        for (int qq = 0; qq < 2; ++qq) {
            const int idx = tid + 128 * qq;      // 0..255
            const int rr = idx >> 3, cc = (idx & 7) * 4;
#pragma unroll
            for (int j = 0; j < 4; ++j) {
                const float4 v = *(const float4*)(xim + (size_t)(ci0 + j) * HW + idx * 4);
                xs[j][1 + rr][1 + cc + 0] = v.x;
                xs[j][1 + rr][1 + cc + 1] = v.y;
                xs[j][1 + rr][1 + cc + 2] = v.z;
                xs[j][1 + rr][1 + cc + 3] = v.w;
            }
        }
        __syncthreads();

#pragma unroll
        for (int j = 0; j < 4; ++j) {
            // weight row base for this (oc-group, input channel): uniform
            const float* wp = w + ((size_t)oc0 * CC + (ci0 + j)) * 9;
#pragma unroll
            for (int dy = 0; dy < 3; ++dy) {
                float xv[10];
#pragma unroll
                for (int k = 0; k < 10; ++k) xv[k] = xs[j][r + dy][c0 + k];
#pragma unroll
                for (int dx = 0; dx < 3; ++dx) {
                    const int tap = dy * 3 + dx;
#pragma unroll
                    for (int o = 0; o < 8; ++o) {
                        const float wv = wp[(size_t)o * CC * 9 + tap];  // uniform -> SGPR
#pragma unroll
                        for (int p = 0; p < 8; ++p)
                            acc[o][p] = fmaf(xv[dx + p], wv, acc[o][p]);
                    }
                }
            }
        }
    }

    // ---- store conv output ----
    float* yim = y + (size_t)n * CHW + (size_t)oc0 * HW + r * WW + c0;
#pragma unroll
    for (int o = 0; o < 8; ++o) {
        *(float4*)(yim + (size_t)o * HW)     = make_float4(acc[o][0], acc[o][1], acc[o][2], acc[o][3]);
        *(float4*)(yim + (size_t)o * HW + 4) = make_float4(acc[o][4], acc[o][5], acc[o][6], acc[o][7]);
    }

    // ---- fused BN partial stats: per-(image, oc) sum & sumsq over plane ----
    float ps[8], ps2[8];
#pragma unroll
    for (int o = 0; o < 8; ++o) {
        float s = 0.0f, s2 = 0.0f;
#pragma unroll
        for (int p = 0; p < 8; ++p) {
            s  += acc[o][p];
            s2  = fmaf(acc[o][p], acc[o][p], s2);
        }
        ps[o] = s; ps2[o] = s2;
    }
#pragma unroll
    for (int off = 32; off > 0; off >>= 1)
#pragma unroll
        for (int o = 0; o < 8; ++o) {
            ps[o]  += __shfl_down(ps[o], off);
            ps2[o] += __shfl_down(ps2[o], off);
        }
    __shared__ float sred[2][2][8];   // [wave][stat][oc]
    const int wid = tid >> 6, lane = tid & 63;
    if (lane == 0) {
#pragma unroll
        for (int o = 0; o < 8; ++o) { sred[wid][0][o] = ps[o]; sred[wid][1][o] = ps2[o]; }
    }
    __syncthreads();
    if (tid < 16) {
        const int st = tid >> 3, o = tid & 7;
        pstats[((size_t)n * CC + oc0 + o) * 2 + st] = sred[0][st][o] + sred[1][st][o];
    }
}

// Reduce 256 per-image partials per channel -> per-channel affine (scale, shift)
__global__ void finalize_kernel(const float* __restrict__ pstats,
                                const float* __restrict__ bn_w,
                                const float* __restrict__ bn_b,
                                float* __restrict__ ss) {
    const int c = threadIdx.x;
    if (c < CC) {
        float s = 0.0f, s2 = 0.0f;
        for (int n = 0; n < NPLANES; ++n) {
            s  += pstats[2 * ((size_t)n * CC + c)];
            s2 += pstats[2 * ((size_t)n * CC + c) + 1];
        }
        const float inv_n = 1.0f / (float)TBHW;
        const float mean  = s * inv_n;
        const float var   = s2 * inv_n - mean * mean;  // biased var
        const float scale = bn_w[c] * rsqrtf(var + 1e-5f);
        ss[c]      = scale;
        ss[CC + c] = bn_b[c] - mean * scale;
    }
}

// ---------------------------------------------------------------------------
// Fused BN-apply + LIF recurrence (in-place: spikes overwrite conv output).
// Thread owns one spatial site across all T. Layer 3 also accumulates the
// pooled spike count per (b,c) (block = 256 consecutive sites = same (b,c)).
// Pooled atomics are sums of {0,1} floats (<=8192): exact & order-independent.
// ---------------------------------------------------------------------------
template <bool POOL>
__global__ __launch_bounds__(256) void bn_lif_kernel(float* __restrict__ y,
                                                     const float* __restrict__ ss,
                                                     float* __restrict__ pooled) {
    const size_t s0 = (size_t)blockIdx.x * 256 + threadIdx.x;  // site in [0,SITES)
    const int c = (int)((s0 >> 10) & (CC - 1));
    const float scale = ss[c], shift = ss[CC + c];
    float mem = 0.0f, spk = 0.0f, cnt = 0.0f;
#pragma unroll
    for (int t = 0; t < TT; ++t) {
        const size_t idx = (size_t)t * SITES + s0;
        const float xv = y[idx] * scale + shift;
        mem = mem * (0.25f * (1.0f - spk)) + xv;   // mem_update, decay=0.25
        spk = (mem > 0.5f) ? 1.0f : 0.0f;          // act_fun, thresh=0.5
        y[idx] = spk;
        if (POOL) cnt += spk;
    }
    if (POOL) {
#pragma unroll
        for (int off = 32; off > 0; off >>= 1) cnt += __shfl_down(cnt, off);
        __shared__ float red[4];
        if ((threadIdx.x & 63) == 0) red[threadIdx.x >> 6] = cnt;
        __syncthreads();
        if (threadIdx.x == 0) {
            const int bc = (int)(s0 >> 10);
            atomicAdd(&pooled[bc], red[0] + red[1] + red[2] + red[3]);
        }
    }
}

// out[b,k] = sum_c pooled[b,c]/(T*H*W) * fc_w[k,c] + fc_b[k]
__global__ void fc_kernel(const float* __restrict__ pooled,
                          const float* __restrict__ fc_w,
                          const float* __restrict__ fc_b,
                          float* __restrict__ out) {
    const int i = blockIdx.x * blockDim.x + threadIdx.x;
    if (i < BB * NCLASS) {
        const int b = i / NCLASS, k = i % NCLASS;
        float acc = 0.0f;
        const float inv = 1.0f / (float)(TT * HW);
        for (int c = 0; c < CC; ++c)
            acc = fmaf(pooled[b * CC + c] * inv, fc_w[k * CC + c], acc);
        out[i] = acc + fc_b[k];
    }
}

extern "C" void kernel_launch(void* const* d_in, const int* in_sizes, int n_in,
                              void* d_out, int out_size, void* d_ws, size_t ws_size,
                              hipStream_t stream) {
    const float* inp    = (const float*)d_in[0];
    const float* cw[3]  = {(const float*)d_in[1], (const float*)d_in[2], (const float*)d_in[3]};
    const float* bnw[3] = {(const float*)d_in[4], (const float*)d_in[6], (const float*)d_in[8]};
    const float* bnb[3] = {(const float*)d_in[5], (const float*)d_in[7], (const float*)d_in[9]};
    const float* fcw    = (const float*)d_in[10];
    const float* fcb    = (const float*)d_in[11];
    float* out = (float*)d_out;

    // workspace layout: two 134.2 MB ping-pong activation buffers + stats
    char*  ws     = (char*)d_ws;
    float* buf0   = (float*)ws;
    float* buf1   = (float*)(ws + (size_t)TT * SITES * sizeof(float));
    float* pstats = (float*)(ws + 2 * (size_t)TT * SITES * sizeof(float));  // 2*NPLANES*CC
    float* ss     = pstats + 2 * NPLANES * CC;
    float* pooled = ss + 2 * CC;

    const float* x = inp;
    float* bufs[2] = {buf0, buf1};
    for (int L = 0; L < 3; ++L) {
        float* y = bufs[L & 1];   // L0->buf0, L1->buf1, L2->buf0 (never in==out)
        conv_kernel<<<CC / 8 * NPLANES, 128, 0, stream>>>(x, cw[L], y, pstats);
        finalize_kernel<<<1, 128, 0, stream>>>(pstats, bnw[L], bnb[L], ss);
        if (L == 2) {
            hipMemsetAsync(pooled, 0, BB * CC * sizeof(float), stream);
            bn_lif_kernel<true><<<SITES / 256, 256, 0, stream>>>(y, ss, pooled);
        } else {
            bn_lif_kernel<false><<<SITES / 256, 256, 0, stream>>>(y, ss, nullptr);
        }
        x = y;
    }
    fc_kernel<<<5, 64, 0, stream>>>(pooled, fcw, fcb, out);
}

// Round 6
// 1087.738 us; speedup vs baseline: 5.9860x; 5.9860x over previous
//
#include <hip/hip_runtime.h>

// Problem constants (T,B,C,H,W = 8,32,128,32,32)
#define TT 8
#define BB 32
#define CC 128
#define HH 32
#define WW 32
#define HW 1024
#define CHW (CC*HW)             // 131072 elems per image
#define NPLANES (TT*BB)         // 256 images
#define SITES (BB*CC*HW)        // 4194304 per timestep
#define TBHW (TT*BB*HH*WW)      // 262144 per channel (BN count)
#define NCLASS 10

typedef __attribute__((ext_vector_type(8))) short bf16x8;
typedef __attribute__((ext_vector_type(4))) float f32x4;
typedef unsigned short u16;
typedef unsigned int u32;

static __device__ __forceinline__ u16 f2bf(float f) {   // RNE fp32->bf16 (finite inputs)
    u32 u = __builtin_bit_cast(u32, f);
    u += 0x7FFFu + ((u >> 16) & 1u);
    return (u16)(u >> 16);
}
static __device__ __forceinline__ float bf2f(u16 h) {
    return __builtin_bit_cast(float, ((u32)h) << 16);
}

// ---------------------------------------------------------------------------
// Weight prep: w[oc][ci][3][3] fp32 -> hi/lo bf16 A-fragment tiles.
// Tile t = (cic*9+tap)*16 + ocg*2 + hl, 64 lanes x 16B. Element map:
// oc = ocg*16 + lane%16 (A row), ci = cic*32 + (lane>>4)*8 + j (A k).
// Total 576 tiles = 294912 u16 = 147456 u16-pairs (one thread each).
// ---------------------------------------------------------------------------
__global__ __launch_bounds__(256) void prep_w(const float* __restrict__ w,
                                              u16* __restrict__ wA) {
    const int p = blockIdx.x * 256 + threadIdx.x;      // 0..147455
    const int off = p & 255, lane = off >> 2, jp = off & 3;
    const int tile = p >> 8;
    const int hl = tile & 1, ocg = (tile >> 1) & 7, tt = tile >> 4;
    const int tap = tt % 9, cic = tt / 9;
    const int oc = ocg * 16 + (lane & 15);
    const int cib = cic * 32 + (lane >> 4) * 8 + jp * 2;
#pragma unroll
    for (int e = 0; e < 2; ++e) {
        const float f = w[((size_t)oc * CC + cib + e) * 9 + tap];
        const u16 h = f2bf(f);
        wA[(size_t)p * 2 + e] = (hl == 0) ? h : f2bf(f - bf2f(h));
    }
}

// ---------------------------------------------------------------------------
// MFMA conv 3x3 (pad 1) + fused BN partial stats.
// Block 256 thr = 4 waves; tile: image n, ALL 128 oc, 256 px (8 rows, quarter q).
// Wave wv: px [wv*64, wv*64+64); acc[8 ocg][4 nf] f32x4 = 128 VGPRs.
// LDS X tile: [10 rows][34 cols][ci 32, pad->40] bf16 (cell stride 80B).
// Staging decode: cell = it%340, kk = it/340 -> adjacent lanes read adjacent
// cells at the same ci octet => each global load is ~2 contiguous row-runs
// per wave instead of 4+ scattered 16-elem runs.
// SPLIT=true: fp32 input, stage hi+lo tiles, 3 MFMA passes (whi*xhi + wlo*xhi
// + whi*xlo). SPLIT=false: bf16 {0,1} spike input, 2 passes.
// Weights: A-frags direct from global (prepped, lane-linear 16B, L2-resident).
// Grid id = q*256 + n -> all 4 quarters of image n on XCD n%8.
// Fragment maps (HW-verified D per m89; A/B per m92/m97 contiguous-K pattern):
//   A[row=lane%16][k=(lane>>4)*8+j], B[k=(lane>>4)*8+j][col=lane%16],
//   D[col=lane&15][row=(lane>>4)*4+reg].
// ---------------------------------------------------------------------------
template <bool SPLIT>
__global__ __launch_bounds__(256) void conv_mfma(const void* __restrict__ xin_,
                                                 const u16* __restrict__ wA,
                                                 float* __restrict__ y,
                                                 float* __restrict__ pstats) {
    extern __shared__ u16 smem[];
    u16* hiT = smem;                  // [10][34][40] = 13600 u16 = 27.2KB
    u16* loT = smem + 13600;          // SPLIT only
    const int tid = threadIdx.x;
    const int id  = blockIdx.x;
    const int n   = id & 255, q = id >> 8;
    const int lane = tid & 63, wv = tid >> 6, kg = lane >> 4, l16 = lane & 15;

    f32x4 acc[8][4];
#pragma unroll
    for (int g = 0; g < 8; ++g)
#pragma unroll
        for (int nf = 0; nf < 4; ++nf) acc[g][nf] = (f32x4){0.f, 0.f, 0.f, 0.f};

    int cell0[4];
#pragma unroll
    for (int nf = 0; nf < 4; ++nf) {
        const int px = wv * 64 + nf * 16 + l16;
        cell0[nf] = (px >> 5) * 34 + (px & 31);
    }

    const float* xf = (const float*)xin_;
    const u16*   xb = (const u16*)xin_;
    const bf16x8* wAv = (const bf16x8*)wA;

    for (int cic = 0; cic < 4; ++cic) {
        __syncthreads();
        // ---- stage 32 ci x 10 rows x 34 cols (zero halo) ----
        for (int it = tid; it < 1360; it += 256) {
            const int kk = it / 340, cell = it - kk * 340;
            const int trow = cell / 34, tcol = cell - trow * 34;
            const int grow = q * 8 - 1 + trow, gcol = tcol - 1;
            const bool ok = ((unsigned)grow < 32u) && ((unsigned)gcol < 32u);
            u16 hh[8], ll[8];
#pragma unroll
            for (int i = 0; i < 8; ++i) {
                const int ci = cic * 32 + kk * 8 + i;
                if (SPLIT) {
                    const float v = ok ? xf[(size_t)(n * CC + ci) * HW + grow * WW + gcol] : 0.0f;
                    const u16 h = f2bf(v);
                    hh[i] = h;
                    ll[i] = f2bf(v - bf2f(h));
                } else {
                    hh[i] = ok ? xb[(size_t)(n * CC + ci) * HW + grow * WW + gcol] : (u16)0;
                }
            }
            const int o = cell * 40 + kk * 8;
            *(int4*)(hiT + o) = make_int4((int)((u32)hh[0] | ((u32)hh[1] << 16)),
                                          (int)((u32)hh[2] | ((u32)hh[3] << 16)),
                                          (int)((u32)hh[4] | ((u32)hh[5] << 16)),
                                          (int)((u32)hh[6] | ((u32)hh[7] << 16)));
            if (SPLIT)
                *(int4*)(loT + o) = make_int4((int)((u32)ll[0] | ((u32)ll[1] << 16)),
                                              (int)((u32)ll[2] | ((u32)ll[3] << 16)),
                                              (int)((u32)ll[4] | ((u32)ll[5] << 16)),
                                              (int)((u32)ll[6] | ((u32)ll[7] << 16)));
        }
        __syncthreads();
        // ---- compute: 9 taps x (2 or 3 passes) ----
#pragma unroll
        for (int tap = 0; tap < 9; ++tap) {
            const int dy = tap / 3, dx = tap % 3;
            bf16x8 ah[8], al[8];
#pragma unroll
            for (int g = 0; g < 8; ++g) {
                const int tb = (cic * 9 + tap) * 16 + g * 2;
                ah[g] = wAv[(size_t)tb * 64 + lane];
                al[g] = wAv[(size_t)(tb + 1) * 64 + lane];
            }
#pragma unroll
            for (int nf = 0; nf < 4; ++nf) {
                const int o = (cell0[nf] + dy * 34 + dx) * 40 + kg * 8;
                const bf16x8 b = *(const bf16x8*)(hiT + o);
#pragma unroll
                for (int g = 0; g < 8; ++g)
                    acc[g][nf] = __builtin_amdgcn_mfma_f32_16x16x32_bf16(ah[g], b, acc[g][nf], 0, 0, 0);
#pragma unroll
                for (int g = 0; g < 8; ++g)
                    acc[g][nf] = __builtin_amdgcn_mfma_f32_16x16x32_bf16(al[g], b, acc[g][nf], 0, 0, 0);
                if (SPLIT) {
                    const bf16x8 bl = *(const bf16x8*)(loT + o);
#pragma unroll
                    for (int g = 0; g < 8; ++g)
                        acc[g][nf] = __builtin_amdgcn_mfma_f32_16x16x32_bf16(ah[g], bl, acc[g][nf], 0, 0, 0);
                }
            }
        }
    }

    // ---- store y (fp32). D map: col(px)=lane&15, row(oc)=(lane>>4)*4+reg ----
    float* yp = y + (size_t)n * CHW + q * 256;
#pragma unroll
    for (int g = 0; g < 8; ++g)
#pragma unroll
        for (int r = 0; r < 4; ++r) {
            const int oc = g * 16 + kg * 4 + r;
#pragma unroll
            for (int nf = 0; nf < 4; ++nf)
                yp[(size_t)oc * HW + wv * 64 + nf * 16 + l16] = acc[g][nf][r];
        }

    // ---- fused BN partial stats over this block's 256 px, all 128 oc ----
    __syncthreads();                       // all LDS compute reads done -> reuse smem
    float* sred = (float*)smem;            // [4 waves][128 oc][2] = 4KB
#pragma unroll
    for (int g = 0; g < 8; ++g)
#pragma unroll
        for (int r = 0; r < 4; ++r) {
            float s = 0.f, s2 = 0.f;
#pragma unroll
            for (int nf = 0; nf < 4; ++nf) {
                const float v = acc[g][nf][r];
                s += v; s2 = fmaf(v, v, s2);
            }
            s  += __shfl_xor(s, 1);  s  += __shfl_xor(s, 2);
            s  += __shfl_xor(s, 4);  s  += __shfl_xor(s, 8);
            s2 += __shfl_xor(s2, 1); s2 += __shfl_xor(s2, 2);
            s2 += __shfl_xor(s2, 4); s2 += __shfl_xor(s2, 8);
            if (l16 == 0) {
                const int oc = g * 16 + kg * 4 + r;
                sred[(wv * 128 + oc) * 2 + 0] = s;
                sred[(wv * 128 + oc) * 2 + 1] = s2;
            }
        }
    __syncthreads();
    if (tid < 128) {
        float s = 0.f, s2 = 0.f;
#pragma unroll
        for (int w2 = 0; w2 < 4; ++w2) {
            s  += sred[(w2 * 128 + tid) * 2 + 0];
            s2 += sred[(w2 * 128 + tid) * 2 + 1];
        }
        pstats[(size_t)id * 256 + tid]       = s;
        pstats[(size_t)id * 256 + 128 + tid] = s2;
    }
}

// Reduce 1024 per-block partials per channel -> affine (scale, shift)
__global__ void finalize_kernel(const float* __restrict__ pstats,
                                const float* __restrict__ bn_w,
                                const float* __restrict__ bn_b,
                                float* __restrict__ ss) {
    const int c = threadIdx.x;
    if (c < CC) {
        float s = 0.f, s2 = 0.f;
        for (int i = 0; i < 1024; ++i) {
            s  += pstats[(size_t)i * 256 + c];
            s2 += pstats[(size_t)i * 256 + 128 + c];
        }
        const float inv_n = 1.0f / (float)TBHW;
        const float mean  = s * inv_n;
        const float var   = s2 * inv_n - mean * mean;   // biased var
        const float scale = bn_w[c] * rsqrtf(var + 1e-5f);
        ss[c]      = scale;
        ss[CC + c] = bn_b[c] - mean * scale;
    }
}

// ---------------------------------------------------------------------------
// Fused BN-apply + LIF. Reads fp32 conv out; writes bf16 spikes (exact {0,1}).
// POOL (last layer): skip spike store, accumulate pooled count per (b,c).
// ---------------------------------------------------------------------------
template <bool POOL>
__global__ __launch_bounds__(256) void bn_lif_kernel(const float* __restrict__ y,
                                                     const float* __restrict__ ss,
                                                     u16* __restrict__ spk,
                                                     float* __restrict__ pooled) {
    const size_t s0 = (size_t)blockIdx.x * 256 + threadIdx.x;
    const int c = (int)((s0 >> 10) & (CC - 1));
    const float scale = ss[c], shift = ss[CC + c];
    float mem = 0.f, sv = 0.f, cnt = 0.f;
#pragma unroll
    for (int t = 0; t < TT; ++t) {
        const size_t idx = (size_t)t * SITES + s0;
        const float xv = y[idx] * scale + shift;
        mem = mem * (0.25f * (1.0f - sv)) + xv;
        sv  = (mem > 0.5f) ? 1.0f : 0.0f;
        if (!POOL) spk[idx] = (mem > 0.5f) ? (u16)0x3F80 : (u16)0;
        if (POOL) cnt += sv;
    }
    if (POOL) {
#pragma unroll
        for (int off = 32; off > 0; off >>= 1) cnt += __shfl_down(cnt, off);
        __shared__ float red[4];
        if ((threadIdx.x & 63) == 0) red[threadIdx.x >> 6] = cnt;
        __syncthreads();
        if (threadIdx.x == 0) {
            const int bc = (int)(s0 >> 10);
            atomicAdd(&pooled[bc], red[0] + red[1] + red[2] + red[3]);
        }
    }
}

__global__ void fc_kernel(const float* __restrict__ pooled,
                          const float* __restrict__ fc_w,
                          const float* __restrict__ fc_b,
                          float* __restrict__ out) {
    const int i = blockIdx.x * blockDim.x + threadIdx.x;
    if (i < BB * NCLASS) {
        const int b = i / NCLASS, k = i % NCLASS;
        float acc = 0.f;
        const float inv = 1.0f / (float)(TT * HW);
        for (int c = 0; c < CC; ++c)
            acc = fmaf(pooled[b * CC + c] * inv, fc_w[k * CC + c], acc);
        out[i] = acc + fc_b[k];
    }
}

extern "C" void kernel_launch(void* const* d_in, const int* in_sizes, int n_in,
                              void* d_out, int out_size, void* d_ws, size_t ws_size,
                              hipStream_t stream) {
    const float* inp    = (const float*)d_in[0];
    const float* cw[3]  = {(const float*)d_in[1], (const float*)d_in[2], (const float*)d_in[3]};
    const float* bnw[3] = {(const float*)d_in[4], (const float*)d_in[6], (const float*)d_in[8]};
    const float* bnb[3] = {(const float*)d_in[5], (const float*)d_in[7], (const float*)d_in[9]};
    const float* fcw    = (const float*)d_in[10];
    const float* fcb    = (const float*)d_in[11];
    float* out = (float*)d_out;

    // ws layout (~203 MB): y fp32 134.2MB | spikes bf16 67.1MB | wA 0.59MB |
    // pstats 1MB | ss | pooled
    char* ws = (char*)d_ws;
    float* bufY   = (float*)ws;
    u16*   bufS   = (u16*)(ws + (size_t)TT * SITES * 4);
    u16*   wA     = (u16*)(ws + (size_t)TT * SITES * 4 + (size_t)TT * SITES * 2);
    float* pstats = (float*)((char*)wA + 589824);
    float* ss     = pstats + 1024 * 256;
    float* pooled = ss + 2 * CC;

    const void* x = (const void*)inp;
    for (int L = 0; L < 3; ++L) {
        prep_w<<<576, 256, 0, stream>>>(cw[L], wA);
        if (L == 0)
            conv_mfma<true><<<1024, 256, 2 * 13600 * sizeof(u16), stream>>>(x, wA, bufY, pstats);
        else
            conv_mfma<false><<<1024, 256, 13600 * sizeof(u16), stream>>>(x, wA, bufY, pstats);
        finalize_kernel<<<1, 128, 0, stream>>>(pstats, bnw[L], bnb[L], ss);
        if (L == 2) {
            hipMemsetAsync(pooled, 0, BB * CC * sizeof(float), stream);
            bn_lif_kernel<true><<<SITES / 256, 256, 0, stream>>>(bufY, ss, nullptr, pooled);
        } else {
            bn_lif_kernel<false><<<SITES / 256, 256, 0, stream>>>(bufY, ss, bufS, nullptr);
        }
        x = (const void*)bufS;
    }
    fc_kernel<<<5, 64, 0, stream>>>(pooled, fcw, fcb, out);
}